// Round 4
// baseline (241.357 us; speedup 1.0000x reference)
//
#include <hip/hip_runtime.h>

#define NB 4
#define NC 64
#define NH 256
#define NW 256
#define TH 32                  // output rows per block (4 waves x 8 rows)
#define SROWS (TH + 6)         // 38 staged input rows (incl. +/-3 halo)
#define LROW 264               // LDS row: 4 zero-pad | 256 data | 4 zero-pad

// ---------- phase 1: per-pixel weight params, shared by all 64 channels ----------
__global__ __launch_bounds__(256)
void wprep(const float* __restrict__ persp,
           const float* __restrict__ alpha_p,
           const float* __restrict__ beta_p,
           const float* __restrict__ gamma_p,
           float* __restrict__ ws)
{
    const float alpha = alpha_p[0];
    const float beta  = beta_p[0];
    const float gamma = gamma_p[0];
    const int i = (blockIdx.x * 256 + threadIdx.x) * 4;
    const float4 p = *(const float4*)(persp + i);
    const float pa[4] = {p.x, p.y, p.z, p.w};
    float g[4], inv2[4];
    #pragma unroll
    for (int k = 0; k < 4; ++k) {
        const float z  = fmaf(beta, pa[k], gamma);
        const float sg = __builtin_amdgcn_rcpf(1.0f + __expf(-z));
        const float sigma = fmaxf(alpha * sg, 1e-4f);
        const float t  = 0.5f * __builtin_amdgcn_rcpf(sigma * sigma);
        const float gg = __expf(-t);
        const float g2 = gg * gg;
        const float p4 = g2 * g2;
        const float p9 = p4 * p4 * gg;
        const float S  = fmaf(2.0f, (gg + p4) + p9, 1.0f);
        const float inv = __builtin_amdgcn_rcpf(S);
        g[k] = gg;
        inv2[k] = inv * inv;
    }
    float* wp = ws + (size_t)i * 2;
    *(float4*)(wp)     = make_float4(g[0], inv2[0], g[1], inv2[1]);
    *(float4*)(wp + 4) = make_float4(g[2], inv2[2], g[3], inv2[3]);
}

// ---------- phase 2: LDS stage + 7x10 register window, 4 waves/SIMD ----------
// Round-2 lesson: 7x12 window + nxt copy -> ~190 total regs -> 2 waves/SIMD,
// VALUBusy 30%. Round-3 lesson: trading the window for LDS re-reads is worse
// (LDS pipe 2.3x). This round: window trimmed to the 10 live columns, direct
// slot refill (no nxt), live set ~120 -> declare (256,4) so the compiler MUST
// fit 128 regs / 4 waves/SIMD. Spill telltale: WRITE_SIZE >> 65536 KB.
__global__ __launch_bounds__(256, 4)
void adaptive_gauss7(const float* __restrict__ x,
                     const float* __restrict__ wsr,
                     float* __restrict__ out)
{
    __shared__ float lds[SROWS * LROW];   // 40,128 B -> exactly 4 blocks/CU

    const int tid  = threadIdx.x;
    const int lane = tid & 63;
    const int wv   = tid >> 6;            // 4 waves x 8 rows = 32 rows
    const int c    = blockIdx.x;
    const int h0   = blockIdx.y * TH;
    const int b    = blockIdx.z;
    const int colbase = lane * 4;         // output cols colbase..colbase+3
    const int rg      = h0 + wv * 8;      // first output row of this wave

    const float* xc   = x   + (size_t)(b * NC + c) * NH * NW;
    float*       outp = out + (size_t)(b * NC + c) * NH * NW;
    const float* wrow = wsr + (size_t)b * NH * NW * 2;

    // side pads: zero 4 floats at both ends of each staged row
    if (tid < SROWS) {
        *(float4*)&lds[tid * LROW]       = make_float4(0.f, 0.f, 0.f, 0.f);
        *(float4*)&lds[tid * LROW + 260] = make_float4(0.f, 0.f, 0.f, 0.f);
    }

    // async stage: wave-interleaved rows, DMA straight to LDS (no VGPR trip)
    for (int r = wv; r < SROWS; r += 4) {
        const int gr = h0 - 3 + r;                     // wave-uniform bound
        if ((unsigned)gr < NH) {
            __builtin_amdgcn_global_load_lds(
                (const __attribute__((address_space(1))) void*)(xc + (size_t)gr * NW + colbase),
                (__attribute__((address_space(3))) void*)&lds[r * LROW + 4],
                16, 0, 0);
        } else {
            *(float4*)&lds[r * LROW + 4 + colbase] = make_float4(0.f, 0.f, 0.f, 0.f);
        }
    }
    __syncthreads();

    // window: 7 rows x 10 cols = cols colbase-3 .. colbase+6 (only live taps).
    // tile row (wv*8 + o + j) lives in slot (o + j) % 7.
    float win[7][10];
    auto fill = [&](float (&dst)[10], int tr) {
        const float* rp = &lds[tr * LROW + colbase];  // cols colbase-4 .. +7
        const float4 a0 = *(const float4*)(rp);
        const float4 a1 = *(const float4*)(rp + 4);
        const float4 a2 = *(const float4*)(rp + 8);
        dst[0] = a0.y; dst[1] = a0.z; dst[2] = a0.w;          // cols -3..-1
        dst[3] = a1.x; dst[4] = a1.y; dst[5] = a1.z; dst[6] = a1.w;  // 0..3
        dst[7] = a2.x; dst[8] = a2.y; dst[9] = a2.z;          // 4..6
    };
    #pragma unroll
    for (int r = 0; r < 7; ++r)
        fill(win[r], wv * 8 + r);

    const float* wp0 = wrow + ((size_t)rg * NW + colbase) * 2;
    float4 wa = *(const float4*)(wp0);          // {g0,i0,g1,i1}
    float4 wb = *(const float4*)(wp0 + 4);      // {g2,i2,g3,i3}

    #pragma unroll
    for (int o = 0; o < 8; ++o) {
        // prefetch next row's weight params (8 regs, one-iteration distance)
        float4 na, nb;
        if (o < 7) {
            const float* wp = wrow + ((size_t)(rg + o + 1) * NW + colbase) * 2;
            na = *(const float4*)(wp);
            nb = *(const float4*)(wp + 4);
        }

        // compute output row rg+o; pixel k taps window cols q = k .. k+6
        const float gk[4] = {wa.x, wa.z, wb.x, wb.z};
        const float iv[4] = {wa.y, wa.w, wb.y, wb.w};
        float res[4];
        #pragma unroll
        for (int k = 0; k < 4; ++k) {
            const float g  = gk[k];
            const float g2 = g * g;
            const float p4 = g2 * g2;
            const float p9 = p4 * p4 * g;

            float rs[7];
            #pragma unroll
            for (int j = 0; j < 7; ++j) {
                const int s = (o + j) % 7;     // static after unroll
                rs[j] = fmaf(p9, win[s][k]     + win[s][k + 6],
                        fmaf(p4, win[s][k + 1] + win[s][k + 5],
                        fmaf(g,  win[s][k + 2] + win[s][k + 4],
                                 win[s][k + 3])));
            }
            const float acc = fmaf(p9, rs[0] + rs[6],
                              fmaf(p4, rs[1] + rs[5],
                              fmaf(g,  rs[2] + rs[4],
                                       rs[3])));
            res[k] = acc * iv[k];
        }
        *(float4*)(outp + (size_t)(rg + o) * NW + colbase) =
            make_float4(res[0], res[1], res[2], res[3]);

        // refill the now-dead slot directly from LDS (use is 1 iteration away)
        if (o < 7) {
            fill(win[o % 7], wv * 8 + o + 7);
            wa = na; wb = nb;
        }
    }
}

extern "C" void kernel_launch(void* const* d_in, const int* in_sizes, int n_in,
                              void* d_out, int out_size, void* d_ws, size_t ws_size,
                              hipStream_t stream) {
    const float* x     = (const float*)d_in[0];
    const float* persp = (const float*)d_in[1];
    const float* alpha = (const float*)d_in[2];
    const float* beta  = (const float*)d_in[3];
    const float* gamma = (const float*)d_in[4];
    float* outp        = (float*)d_out;
    float* ws          = (float*)d_ws;       // 4*256*256*2 floats = 2 MiB

    wprep<<<dim3((NB * NH * NW) / 1024), dim3(256), 0, stream>>>(persp, alpha, beta, gamma, ws);
    adaptive_gauss7<<<dim3(NC, NH / TH, NB), dim3(256), 0, stream>>>(x, ws, outp);
}

// Round 5
// 138.933 us; speedup vs baseline: 1.7372x; 1.7372x over previous
//
#include <hip/hip_runtime.h>

#define NB 4
#define NC 64
#define NH 256
#define NW 256
#define TH 32                  // output rows per block (4 waves x 8 rows)
#define SROWS (TH + 6)         // 38 staged input rows (incl. +/-3 halo)
#define LROW 264               // LDS row: 4 zero-pad | 256 data | 4 zero-pad

// ---------- phase 1: per-pixel weight params, shared by all 64 channels ----------
__global__ __launch_bounds__(256)
void wprep(const float* __restrict__ persp,
           const float* __restrict__ alpha_p,
           const float* __restrict__ beta_p,
           const float* __restrict__ gamma_p,
           float* __restrict__ ws)
{
    const float alpha = alpha_p[0];
    const float beta  = beta_p[0];
    const float gamma = gamma_p[0];
    const int i = (blockIdx.x * 256 + threadIdx.x) * 4;
    const float4 p = *(const float4*)(persp + i);
    const float pa[4] = {p.x, p.y, p.z, p.w};
    float g[4], inv2[4];
    #pragma unroll
    for (int k = 0; k < 4; ++k) {
        const float z  = fmaf(beta, pa[k], gamma);
        const float sg = __builtin_amdgcn_rcpf(1.0f + __expf(-z));
        const float sigma = fmaxf(alpha * sg, 1e-4f);
        const float t  = 0.5f * __builtin_amdgcn_rcpf(sigma * sigma);
        const float gg = __expf(-t);
        const float g2 = gg * gg;
        const float p4 = g2 * g2;
        const float p9 = p4 * p4 * gg;
        const float S  = fmaf(2.0f, (gg + p4) + p9, 1.0f);
        const float inv = __builtin_amdgcn_rcpf(S);
        g[k] = gg;
        inv2[k] = inv * inv;
    }
    float* wp = ws + (size_t)i * 2;
    *(float4*)(wp)     = make_float4(g[0], inv2[0], g[1], inv2[1]);
    *(float4*)(wp + 4) = make_float4(g[2], inv2[2], g[3], inv2[3]);
}

// ---------- phase 2: LDS stage + 7x10 register window, 3 waves/SIMD ----------
// Register-budget ledger (hard-won):
//   (256,2): budget 256 -> allocator AGPR-splits at 84 arch, 2 w/SIMD, 44 us
//   (256,4): budget 128 -> 64 arch + SCRATCH SPILL (WRITE 65->331 MB), 150 us
//   (256,3): budget 168, live set ~110 -> should fit in arch VGPRs, 3 w/SIMD.
// Spill telltale: WRITE_SIZE >> 65536 KB. AGPR-split telltale: VGPR ~84.
__global__ __launch_bounds__(256, 3)
void adaptive_gauss7(const float* __restrict__ x,
                     const float* __restrict__ wsr,
                     float* __restrict__ out)
{
    __shared__ float lds[SROWS * LROW];   // 40,128 B -> 4 blocks/CU max by LDS

    const int tid  = threadIdx.x;
    const int lane = tid & 63;
    const int wv   = tid >> 6;            // 4 waves x 8 rows = 32 rows
    const int c    = blockIdx.x;
    const int h0   = blockIdx.y * TH;
    const int b    = blockIdx.z;
    const int colbase = lane * 4;         // output cols colbase..colbase+3
    const int rg      = h0 + wv * 8;      // first output row of this wave

    const float* xc   = x   + (size_t)(b * NC + c) * NH * NW;
    float*       outp = out + (size_t)(b * NC + c) * NH * NW;
    const float* wrow = wsr + (size_t)b * NH * NW * 2;

    // side pads: zero 4 floats at both ends of each staged row
    if (tid < SROWS) {
        *(float4*)&lds[tid * LROW]       = make_float4(0.f, 0.f, 0.f, 0.f);
        *(float4*)&lds[tid * LROW + 260] = make_float4(0.f, 0.f, 0.f, 0.f);
    }

    // async stage: wave-interleaved rows, DMA straight to LDS (no VGPR trip)
    for (int r = wv; r < SROWS; r += 4) {
        const int gr = h0 - 3 + r;                     // wave-uniform bound
        if ((unsigned)gr < NH) {
            __builtin_amdgcn_global_load_lds(
                (const __attribute__((address_space(1))) void*)(xc + (size_t)gr * NW + colbase),
                (__attribute__((address_space(3))) void*)&lds[r * LROW + 4],
                16, 0, 0);
        } else {
            *(float4*)&lds[r * LROW + 4 + colbase] = make_float4(0.f, 0.f, 0.f, 0.f);
        }
    }
    __syncthreads();

    // window: 7 rows x 10 cols = cols colbase-3 .. colbase+6 (only live taps).
    // tile row (wv*8 + o + j) lives in slot (o + j) % 7.
    float win[7][10];
    auto fill = [&](float (&dst)[10], int tr) {
        const float* rp = &lds[tr * LROW + colbase];  // cols colbase-4 .. +7
        const float4 a0 = *(const float4*)(rp);
        const float4 a1 = *(const float4*)(rp + 4);
        const float4 a2 = *(const float4*)(rp + 8);
        dst[0] = a0.y; dst[1] = a0.z; dst[2] = a0.w;          // cols -3..-1
        dst[3] = a1.x; dst[4] = a1.y; dst[5] = a1.z; dst[6] = a1.w;  // 0..3
        dst[7] = a2.x; dst[8] = a2.y; dst[9] = a2.z;          // 4..6
    };
    #pragma unroll
    for (int r = 0; r < 7; ++r)
        fill(win[r], wv * 8 + r);

    const float* wp0 = wrow + ((size_t)rg * NW + colbase) * 2;
    float4 wa = *(const float4*)(wp0);          // {g0,i0,g1,i1}
    float4 wb = *(const float4*)(wp0 + 4);      // {g2,i2,g3,i3}

    #pragma unroll
    for (int o = 0; o < 8; ++o) {
        // prefetch next row's weight params (8 regs, one-iteration distance)
        float4 na, nb;
        if (o < 7) {
            const float* wp = wrow + ((size_t)(rg + o + 1) * NW + colbase) * 2;
            na = *(const float4*)(wp);
            nb = *(const float4*)(wp + 4);
        }

        // compute output row rg+o; pixel k taps window cols q = k .. k+6
        const float gk[4] = {wa.x, wa.z, wb.x, wb.z};
        const float iv[4] = {wa.y, wa.w, wb.y, wb.w};
        float res[4];
        #pragma unroll
        for (int k = 0; k < 4; ++k) {
            const float g  = gk[k];
            const float g2 = g * g;
            const float p4 = g2 * g2;
            const float p9 = p4 * p4 * g;

            float rs[7];
            #pragma unroll
            for (int j = 0; j < 7; ++j) {
                const int s = (o + j) % 7;     // static after unroll
                rs[j] = fmaf(p9, win[s][k]     + win[s][k + 6],
                        fmaf(p4, win[s][k + 1] + win[s][k + 5],
                        fmaf(g,  win[s][k + 2] + win[s][k + 4],
                                 win[s][k + 3])));
            }
            const float acc = fmaf(p9, rs[0] + rs[6],
                              fmaf(p4, rs[1] + rs[5],
                              fmaf(g,  rs[2] + rs[4],
                                       rs[3])));
            res[k] = acc * iv[k];
        }
        *(float4*)(outp + (size_t)(rg + o) * NW + colbase) =
            make_float4(res[0], res[1], res[2], res[3]);

        // refill the now-dead slot directly from LDS (use is 1 iteration away)
        if (o < 7) {
            fill(win[o % 7], wv * 8 + o + 7);
            wa = na; wb = nb;
        }
    }
}

extern "C" void kernel_launch(void* const* d_in, const int* in_sizes, int n_in,
                              void* d_out, int out_size, void* d_ws, size_t ws_size,
                              hipStream_t stream) {
    const float* x     = (const float*)d_in[0];
    const float* persp = (const float*)d_in[1];
    const float* alpha = (const float*)d_in[2];
    const float* beta  = (const float*)d_in[3];
    const float* gamma = (const float*)d_in[4];
    float* outp        = (float*)d_out;
    float* ws          = (float*)d_ws;       // 4*256*256*2 floats = 2 MiB

    wprep<<<dim3((NB * NH * NW) / 1024), dim3(256), 0, stream>>>(persp, alpha, beta, gamma, ws);
    adaptive_gauss7<<<dim3(NC, NH / TH, NB), dim3(256), 0, stream>>>(x, ws, outp);
}